// Round 10
// baseline (3450.451 us; speedup 1.0000x reference)
//
#include <hip/hip_runtime.h>
#include <cmath>

// Shapes: B=128, D=192, DEPTH=12, H=3(hd=64), E=4, N=65(tokens), NC=100, WIN_HALF=3
#define ROWS 8320
#define DD   192

typedef __attribute__((ext_vector_type(8))) _Float16 half8;
typedef __attribute__((ext_vector_type(4))) float floatx4;

#define GLD16(gp, lp) __builtin_amdgcn_global_load_lds( \
    (const __attribute__((address_space(1))) void*)(gp), \
    (__attribute__((address_space(3))) void*)(lp), 16, 0, 0)

#define MFMA_F16 __builtin_amdgcn_mfma_f32_16x16x32_f16

__device__ __forceinline__ float gelu_f(float x) {
    return 0.5f * x * (1.0f + erff(x * 0.70710678118654752440f));
}

// block-wide sum for blockDim.x == 192 (embed only)
__device__ __forceinline__ float blk_sum_192(float v, float* sbuf) {
    int tid = threadIdx.x;
    sbuf[tid] = v;
    __syncthreads();
    for (int off = 96; off >= 3; off >>= 1) {
        if (tid < off) sbuf[tid] += sbuf[tid + off];
        __syncthreads();
    }
    float r = sbuf[0] + sbuf[1] + sbuf[2];
    __syncthreads();
    return r;
}

// ---------------- flat fp32 -> fp16 ----------------
__global__ __launch_bounds__(256) void cvt_h_kernel(
    const float* __restrict__ s, _Float16* __restrict__ d, long n8)
{
    long i = (long)blockIdx.x * 256 + threadIdx.x;
    if (i >= n8) return;
    const float* sp = s + i * 8;
    _Float16* dp = d + i * 8;
    #pragma unroll
    for (int j = 0; j < 8; j++) dp[j] = (_Float16)sp[j];
}

// e_w2 (12,4,192,384) -> fp16 cat layout [l][n][K'=1536] with col = e*384+k
__global__ __launch_bounds__(256) void permw2h_kernel(
    const float* __restrict__ s, _Float16* __restrict__ d)
{
    long i = (long)blockIdx.x * 256 + threadIdx.x;   // (l, n, p), p in 0..191
    if (i >= (long)12 * 192 * 192) return;
    int l = (int)(i / (192 * 192));
    int rem = (int)(i % (192 * 192));
    int n = rem / 192, p = rem % 192;
    int c0 = p * 8;
    int e = c0 / 384, k0 = c0 % 384;
    const float* sp = s + (((size_t)l * 4 + e) * 192 + n) * 384 + k0;
    _Float16* dp = d + i * 8;
    #pragma unroll
    for (int j = 0; j < 8; j++) dp[j] = (_Float16)sp[j];
}

// ---------------- patch embed + LN + cls + pos (fp32) ----------------
__global__ __launch_bounds__(192) void embed_kernel(
    const float* __restrict__ x, const float* __restrict__ conv_w,
    const float* __restrict__ conv_b, const float* __restrict__ pe_g,
    const float* __restrict__ pe_b, const float* __restrict__ cls_tok,
    const float* __restrict__ pos, float* __restrict__ t)
{
    __shared__ float patch[48];
    __shared__ float red[192];
    int blk = blockIdx.x;
    int b = blk / 65, n = blk % 65;
    int tid = threadIdx.x;
    if (n == 0) {
        t[(size_t)b * 65 * DD + tid] = cls_tok[tid] + pos[tid];
        return;
    }
    int p = n - 1, gy = p / 8, gx = p % 8;
    if (tid < 48) {
        int c = tid / 16, iy = (tid % 16) / 4, ix = tid % 4;
        patch[tid] = x[((size_t)b * 3 + c) * 1024 + (size_t)(gy * 4 + iy) * 32 + (gx * 4 + ix)];
    }
    __syncthreads();
    float s = conv_b[tid];
    const float* w = conv_w + (size_t)tid * 48;
    #pragma unroll
    for (int f = 0; f < 48; f++) s += patch[f] * w[f];
    float mean = blk_sum_192(s, red) * (1.0f / 192.0f);
    float d = s - mean;
    float var = blk_sum_192(d * d, red) * (1.0f / 192.0f);
    float o = d * rsqrtf(var + 1e-5f) * pe_g[tid] + pe_b[tid];
    t[((size_t)b * 65 + n) * DD + tid] = o + pos[(size_t)n * DD + tid];
}

// ---------------- LayerNorm (final LN only): wave-per-row + ctb fold ----------------
__global__ __launch_bounds__(256) void ln_kernel(
    const float* __restrict__ in, const float* __restrict__ ctb,
    float* __restrict__ yf,
    const float* __restrict__ g, const float* __restrict__ bb, long in_stride, int nrows)
{
    int wave = threadIdx.x >> 6, lane = threadIdx.x & 63;
    int r = blockIdx.x * 4 + wave;
    if (r >= nrows) return;
    const float* row = in + (size_t)r * in_stride;
    float v0 = row[lane], v1 = row[lane + 64], v2 = row[lane + 128];
    if (ctb) {
        long gr = (long)r * (in_stride / DD);
        const float* cb = ctb + gr * 384;
        v0 += cb[lane] + cb[192 + lane];
        v1 += cb[lane + 64] + cb[256 + lane];
        v2 += cb[lane + 128] + cb[320 + lane];
    }
    float s = v0 + v1 + v2;
    #pragma unroll
    for (int off = 32; off > 0; off >>= 1) s += __shfl_xor(s, off);
    float mean = s * (1.0f / 192.0f);
    float d0 = v0 - mean, d1 = v1 - mean, d2 = v2 - mean;
    float q = d0 * d0 + d1 * d1 + d2 * d2;
    #pragma unroll
    for (int off = 32; off > 0; off >>= 1) q += __shfl_xor(q, off);
    float rstd = rsqrtf(q * (1.0f / 192.0f) + 1e-5f);
    float* yr = yf + (size_t)r * DD;
    yr[lane] = d0 * rstd * g[lane] + bb[lane];
    yr[lane + 64] = d1 * rstd * g[lane + 64] + bb[lane + 64];
    yr[lane + 128] = d2 * rstd * g[lane + 128] + bb[lane + 128];
}

// ---------------- fused attention path: ln1 -> qkv -> banded attn -> proj+res -> ln2+gate ----
// grid 256 = (image b, half s). Q rows: s?33..64:0..32; K/V halo rows s?30..64:0..35.
// Reads tA (+ctb fold), writes tB (post-residual), yhb (ln2 out fp16), expert lists.
__global__ __launch_bounds__(256) void layer_attn_kernel(
    const float* __restrict__ tA, float* __restrict__ tB,
    const float* __restrict__ ctb,
    const _Float16* __restrict__ qw, const _Float16* __restrict__ pw,
    const float* __restrict__ pb, const float* __restrict__ asc,
    const float* __restrict__ temp,
    const float* __restrict__ n1g, const float* __restrict__ n1b,
    const float* __restrict__ n2g, const float* __restrict__ n2b,
    const float* __restrict__ gwm, const float* __restrict__ gb,
    _Float16* __restrict__ yhb,
    int* __restrict__ cnt, int* __restrict__ list, float* __restrict__ wlist)
{
    __shared__ __align__(16) _Float16 ylds[48 * 200];     // y, later o (19.2KB)
    __shared__ __align__(16) _Float16 qkvlds[48 * 584];   // qkv, later tn fp32 (56KB)
    __shared__ __align__(16) _Float16 wlds[192 * 192];    // weight stage (72KB)
    __shared__ float plds[33 * 3 * 8];                    // softmax probs (3.2KB)

    const int tid = threadIdx.x;
    const int lane = tid & 63, wave = tid >> 6;
    const int lr = lane & 15, quad = lane >> 4;
    const int b = blockIdx.x >> 1, s = blockIdx.x & 1;
    const int qlo = s ? 33 : 0, nq = s ? 32 : 33;
    const int klo = s ? 30 : 0, nk = s ? 35 : 36;
    const int qoff = qlo - klo;

    floatx4 zero = {0.f, 0.f, 0.f, 0.f};

    // issue qkv-W stage0 loads (covered by LN1 phase)
    #pragma unroll
    for (int i = 0; i < 18; i++) {
        int sl = i * 256 + tid;
        int rr = sl / 24, c = sl % 24;
        GLD16(qw + (size_t)rr * 192 + (c ^ (rr & 7)) * 8, (char*)wlds + sl * 16);
    }

    // Phase 1: LN1 (+ctb fold) -> ylds fp16
    for (int rl = wave; rl < nk; rl += 4) {
        int gr = b * 65 + klo + rl;
        const float* row = tA + (size_t)gr * DD;
        float v0 = row[lane], v1 = row[lane + 64], v2 = row[lane + 128];
        if (ctb) {
            const float* cb = ctb + (size_t)gr * 384;
            v0 += cb[lane] + cb[192 + lane];
            v1 += cb[lane + 64] + cb[256 + lane];
            v2 += cb[lane + 128] + cb[320 + lane];
        }
        float sm = v0 + v1 + v2;
        #pragma unroll
        for (int off = 32; off > 0; off >>= 1) sm += __shfl_xor(sm, off);
        float mean = sm * (1.0f / 192.0f);
        float d0 = v0 - mean, d1 = v1 - mean, d2 = v2 - mean;
        float q = d0 * d0 + d1 * d1 + d2 * d2;
        #pragma unroll
        for (int off = 32; off > 0; off >>= 1) q += __shfl_xor(q, off);
        float rstd = rsqrtf(q * (1.0f / 192.0f) + 1e-5f);
        ylds[rl * 200 + lane]       = (_Float16)(d0 * rstd * n1g[lane] + n1b[lane]);
        ylds[rl * 200 + lane + 64]  = (_Float16)(d1 * rstd * n1g[lane + 64] + n1b[lane + 64]);
        ylds[rl * 200 + lane + 128] = (_Float16)(d2 * rstd * n1g[lane + 128] + n1b[lane + 128]);
    }
    __syncthreads();   // B1: ylds visible, W0 drained (covered by LN)

    // Phase 2: qkv GEMM, 3 col-stages of 192
    for (int cs = 0; cs < 3; cs++) {
        if (cs > 0) {
            __syncthreads();             // protect wlds (prev stage's reads done)
            #pragma unroll
            for (int i = 0; i < 18; i++) {
                int sl = i * 256 + tid;
                int rr = sl / 24, c = sl % 24;
                GLD16(qw + ((size_t)cs * 192 + rr) * 192 + (c ^ (rr & 7)) * 8,
                      (char*)wlds + sl * 16);
            }
            __syncthreads();             // drain (exposed; ~72KB fill)
        }
        #pragma unroll
        for (int mi = 0; mi < 3; mi++) {
            floatx4 acc[3];
            acc[0] = zero; acc[1] = zero; acc[2] = zero;
            #pragma unroll
            for (int m = 0; m < 6; m++) {
                int ar = mi * 16 + lr;
                half8 a = *(const half8*)(ylds + ar * 200 + m * 32 + quad * 8);
                #pragma unroll
                for (int ni = 0; ni < 3; ni++) {
                    int n = wave * 48 + ni * 16 + lr;
                    half8 w = *(const half8*)(wlds + ((size_t)n * 24 + ((m * 4 + quad) ^ (n & 7))) * 8);
                    acc[ni] = MFMA_F16(a, w, acc[ni], 0, 0, 0);
                }
            }
            #pragma unroll
            for (int ni = 0; ni < 3; ni++)
                #pragma unroll
                for (int r = 0; r < 4; r++) {
                    int row = mi * 16 + quad * 4 + r;
                    int ncol = cs * 192 + wave * 48 + ni * 16 + lr;
                    float v = acc[ni][r];
                    float vp = __shfl_xor(v, 1);
                    if ((lane & 1) == 0) {
                        union { _Float16 h[2]; unsigned u; } pk;
                        pk.h[0] = (_Float16)v; pk.h[1] = (_Float16)vp;
                        *(unsigned*)(qkvlds + (size_t)row * 584 + (ncol & ~1)) = pk.u;
                    }
                }
        }
    }
    __syncthreads();   // B6: qkv visible; wlds free; ylds free

    // issue proj-W loads (covered by attention phase)
    #pragma unroll
    for (int i = 0; i < 18; i++) {
        int sl = i * 256 + tid;
        int rr = sl / 24, c = sl % 24;
        GLD16(pw + (size_t)rr * 192 + (c ^ (rr & 7)) * 8, (char*)wlds + sl * 16);
    }

    // Phase 3a: banded attention scores + softmax
    if (tid < nq * 3) {
        int iq = tid / 3, h = tid % 3;
        int ti = qlo + iq;
        float coef = 0.125f / temp[h];
        const _Float16* qrow = qkvlds + (size_t)(qoff + iq) * 584 + h * 64;
        float sc[7]; float mx = -1e30f;
        #pragma unroll
        for (int jo = 0; jo < 7; jo++) {
            int tj = ti - 3 + jo;
            if (tj >= 0 && tj < 65) {
                const _Float16* krow = qkvlds + (size_t)(tj - klo) * 584 + 192 + h * 64;
                float ss = 0.f;
                #pragma unroll
                for (int d = 0; d < 64; d++) ss += (float)qrow[d] * (float)krow[d];
                sc[jo] = ss * coef; mx = fmaxf(mx, sc[jo]);
            } else sc[jo] = -1e30f;
        }
        float sum = 0.f;
        #pragma unroll
        for (int jo = 0; jo < 7; jo++) {
            float e = expf(sc[jo] - mx);
            plds[(iq * 3 + h) * 8 + jo] = e;
            sum += e;
        }
        float inv = 1.0f / sum;
        #pragma unroll
        for (int jo = 0; jo < 7; jo++) plds[(iq * 3 + h) * 8 + jo] *= inv;
    }
    __syncthreads();   // B7: probs visible

    // Phase 3b: attention output -> ylds (o), fp16
    for (int idx = tid; idx < nq * 192; idx += 256) {
        int iq = idx / 192, c = idx % 192;
        int h = c >> 6, d = c & 63;
        int ti = qlo + iq;
        float ss = 0.f;
        #pragma unroll
        for (int jo = 0; jo < 7; jo++) {
            int tj = ti - 3 + jo;
            if (tj >= 0 && tj < 65)
                ss += plds[(iq * 3 + h) * 8 + jo]
                    * (float)qkvlds[(size_t)(tj - klo) * 584 + 384 + h * 64 + d];
        }
        ylds[iq * 200 + c] = (_Float16)ss;
    }
    __syncthreads();   // B8: o visible; projW drained (covered by attention)

    // Phase 4: proj + residual; write tB + tn LDS (aliased over qkvlds)
    float* tn = (float*)qkvlds;
    float sca = asc[0];
    #pragma unroll
    for (int mi = 0; mi < 3; mi++) {
        floatx4 acc[3];
        acc[0] = zero; acc[1] = zero; acc[2] = zero;
        #pragma unroll
        for (int m = 0; m < 6; m++) {
            int ar = mi * 16 + lr;
            half8 a = *(const half8*)(ylds + ar * 200 + m * 32 + quad * 8);
            #pragma unroll
            for (int ni = 0; ni < 3; ni++) {
                int n = wave * 48 + ni * 16 + lr;
                half8 w = *(const half8*)(wlds + ((size_t)n * 24 + ((m * 4 + quad) ^ (n & 7))) * 8);
                acc[ni] = MFMA_F16(a, w, acc[ni], 0, 0, 0);
            }
        }
        #pragma unroll
        for (int ni = 0; ni < 3; ni++)
            #pragma unroll
            for (int r = 0; r < 4; r++) {
                int row = mi * 16 + quad * 4 + r;
                int n = wave * 48 + ni * 16 + lr;
                if (row < nq) {
                    int gr = b * 65 + qlo + row;
                    float base = tA[(size_t)gr * DD + n];
                    if (ctb) base += ctb[(size_t)gr * 384 + n] + ctb[(size_t)gr * 384 + 192 + n];
                    float v = base + sca * (acc[ni][r] + pb[n]);
                    tB[(size_t)gr * DD + n] = v;
                    tn[row * 196 + n] = v;
                }
            }
    }
    __syncthreads();   // B9: tn visible

    // Phase 5: ln2 + gate top2 + list append
    for (int rl = wave; rl < nq; rl += 4) {
        int gr = b * 65 + qlo + rl;
        float v0 = tn[rl * 196 + lane], v1 = tn[rl * 196 + 64 + lane], v2 = tn[rl * 196 + 128 + lane];
        float sm = v0 + v1 + v2;
        #pragma unroll
        for (int off = 32; off > 0; off >>= 1) sm += __shfl_xor(sm, off);
        float mean = sm * (1.0f / 192.0f);
        float d0 = v0 - mean, d1 = v1 - mean, d2 = v2 - mean;
        float q = d0 * d0 + d1 * d1 + d2 * d2;
        #pragma unroll
        for (int off = 32; off > 0; off >>= 1) q += __shfl_xor(q, off);
        float rstd = rsqrtf(q * (1.0f / 192.0f) + 1e-5f);
        float o0 = d0 * rstd * n2g[lane] + n2b[lane];
        float o1 = d1 * rstd * n2g[lane + 64] + n2b[lane + 64];
        float o2 = d2 * rstd * n2g[lane + 128] + n2b[lane + 128];
        _Float16* yr = yhb + (size_t)gr * DD;
        yr[lane] = (_Float16)o0; yr[lane + 64] = (_Float16)o1; yr[lane + 128] = (_Float16)o2;
        float pe[4];
        #pragma unroll
        for (int e = 0; e < 4; e++) {
            const float* w = gwm + (size_t)e * DD;
            pe[e] = o0 * w[lane] + o1 * w[lane + 64] + o2 * w[lane + 128];
            #pragma unroll
            for (int off = 32; off > 0; off >>= 1) pe[e] += __shfl_xor(pe[e], off);
        }
        if (lane == 0) {
            #pragma unroll
            for (int e = 0; e < 4; e++) pe[e] += gb[e];
            float mx = fmaxf(fmaxf(pe[0], pe[1]), fmaxf(pe[2], pe[3]));
            float ex[4];
            #pragma unroll
            for (int e = 0; e < 4; e++) ex[e] = expf(pe[e] - mx);
            int i0 = 0;
            #pragma unroll
            for (int e = 1; e < 4; e++) if (ex[e] > ex[i0]) i0 = e;
            int i1 = (i0 == 0) ? 1 : 0;
            #pragma unroll
            for (int e = 0; e < 4; e++) if (e != i0 && ex[e] > ex[i1]) i1 = e;
            float denom = ex[i0] + ex[i1];
            int idx0 = atomicAdd(&cnt[i0], 1);
            list[(size_t)i0 * ROWS + idx0] = (gr << 1) | 0;
            wlist[(size_t)i0 * ROWS + idx0] = ex[i0] / denom;
            int idx1 = atomicAdd(&cnt[i1], 1);
            list[(size_t)i1 * ROWS + idx1] = (gr << 1) | 1;
            wlist[(size_t)i1 * ROWS + idx1] = ex[i1] / denom;
        }
    }
}

// ---------------- fused MoE (round-8 proven): fp16, expert-parallel, rank-indexed ----------------
// grid (260, 4): block = 32 gathered rows of expert e. 6 iters of 64 h-cols.
// ctb[row][rank][192] = mlp_sc * w * (gelu(y@w1_e^T+b1_e)@w2_e^T + b2_e)
__global__ __launch_bounds__(256) void moe_kernel(
    const _Float16* __restrict__ yh, const _Float16* __restrict__ w1,
    const _Float16* __restrict__ w2, const float* __restrict__ b1,
    const float* __restrict__ b2, const float* __restrict__ scale,
    const int* __restrict__ cnt, const int* __restrict__ list,
    const float* __restrict__ wlist, float* __restrict__ ctb)
{
    __shared__ __align__(16) _Float16 As[32 * 192];
    __shared__ __align__(16) _Float16 W1s[64 * 192];
    __shared__ __align__(16) _Float16 W2s[192 * 64];
    __shared__ __align__(16) _Float16 Hs[32 * 64];
    __shared__ int   rl[32];
    __shared__ int   rk[32];
    __shared__ float wl[32];
    const int e  = blockIdx.y;
    const int cnte = cnt[e];
    const int r0 = blockIdx.x * 32;
    if (r0 >= cnte) return;
    const int tid = threadIdx.x;
    const int lane = tid & 63, wave = tid >> 6;
    const int lr = lane & 15, quad = lane >> 4;
    const int wr = (wave & 1) * 16;
    const int wc1 = (wave >> 1) * 16;
    const int wc2 = (wave >> 1) * 96;

    if (tid < 32) {
        int sl = r0 + tid;
        bool ok = sl < cnte;
        int v = ok ? list[(size_t)e * ROWS + sl] : 0;
        rl[tid] = v >> 1;
        rk[tid] = ok ? (v & 1) : -1;
        wl[tid] = ok ? wlist[(size_t)e * ROWS + sl] : 0.f;
    }
    __syncthreads();

    #pragma unroll
    for (int i = 0; i < 3; i++) {
        int s = (wave * 3 + i) * 64 + lane;
        int rr = s / 24, c = s % 24;
        GLD16(yh + (size_t)rl[rr] * 192 + (c ^ (rr & 7)) * 8,
              (char*)As + (size_t)(wave * 3 + i) * 1024);
    }
    #pragma unroll
    for (int i = 0; i < 6; i++) {
        int s = (wave * 6 + i) * 64 + lane;
        int rr = s / 24, c = s % 24;
        GLD16(w1 + ((size_t)e * 384 + rr) * 192 + (c ^ (rr & 7)) * 8,
              (char*)W1s + (size_t)(wave * 6 + i) * 1024);
    }
    __syncthreads();

    floatx4 zero = {0.f, 0.f, 0.f, 0.f};
    floatx4 acc2[6];
    #pragma unroll
    for (int j = 0; j < 6; j++) acc2[j] = zero;

    for (int nc = 0; nc < 6; nc++) {
        int ncg = e * 6 + nc;
        #pragma unroll
        for (int i = 0; i < 6; i++) {
            int s = (wave * 6 + i) * 64 + lane;
            int n = s >> 3, c = s & 7;
            GLD16(w2 + (size_t)n * 1536 + (ncg * 8 + (c ^ (n & 7))) * 8,
                  (char*)W2s + (size_t)(wave * 6 + i) * 1024);
        }
        floatx4 acc1[2];
        acc1[0] = zero; acc1[1] = zero;
        #pragma unroll
        for (int m = 0; m < 6; m++) {
            int ar = wr + lr;
            int ch = m * 4 + quad;
            half8 a = *(const half8*)(As + ((size_t)ar * 24 + (ch ^ (ar & 7))) * 8);
            #pragma unroll
            for (int tc = 0; tc < 2; tc++) {
                int cr = wc1 + tc * 32 + lr;
                half8 w = *(const half8*)(W1s + ((size_t)cr * 24 + (ch ^ (cr & 7))) * 8);
                acc1[tc] = MFMA_F16(a, w, acc1[tc], 0, 0, 0);
            }
        }
        #pragma unroll
        for (int tc = 0; tc < 2; tc++)
            #pragma unroll
            for (int r = 0; r < 4; r++) {
                int hrow = wr + quad * 4 + r;
                int hcol = wc1 + tc * 32 + lr;
                float v = gelu_f(acc1[tc][r] + b1[64 * ncg + hcol]) * wl[hrow];
                float vp = __shfl_xor(v, 1);
                if ((lane & 1) == 0) {
                    union { _Float16 h[2]; unsigned u; } pk;
                    pk.h[0] = (_Float16)v;
                    pk.h[1] = (_Float16)vp;
                    int cl = (hcol >> 3) ^ (hrow & 7);
                    *(unsigned*)(Hs + ((size_t)hrow * 8 + cl) * 8 + (hcol & 7)) = pk.u;
                }
            }
        __syncthreads();
        if (nc < 5) {
            #pragma unroll
            for (int i = 0; i < 6; i++) {
                int s = (wave * 6 + i) * 64 + lane;
                int rr = s / 24, c = s % 24;
                GLD16(w1 + ((size_t)e * 384 + (nc + 1) * 64 + rr) * 192 + (c ^ (rr & 7)) * 8,
                      (char*)W1s + (size_t)(wave * 6 + i) * 1024);
            }
        }
        #pragma unroll
        for (int kk = 0; kk < 2; kk++) {
            int ar = wr + lr;
            int ch = kk * 4 + quad;
            half8 a = *(const half8*)(Hs + ((size_t)ar * 8 + (ch ^ (ar & 7))) * 8);
            #pragma unroll
            for (int tj = 0; tj < 6; tj++) {
                int cr = wc2 + tj * 16 + lr;
                half8 w = *(const half8*)(W2s + ((size_t)cr * 8 + (ch ^ (cr & 7))) * 8);
                acc2[tj] = MFMA_F16(a, w, acc2[tj], 0, 0, 0);
            }
        }
        __syncthreads();
    }

    float sc = scale[0];
    #pragma unroll
    for (int tj = 0; tj < 6; tj++) {
        int gcol = wc2 + tj * 16 + lr;
        #pragma unroll
        for (int r = 0; r < 4; r++) {
            int lrow = wr + quad * 4 + r;
            int rank = rk[lrow];
            if (rank >= 0) {
                float v = sc * (acc2[tj][r] + wl[lrow] * b2[e * 192 + gcol]);
                ctb[((size_t)rl[lrow] * 2 + rank) * 192 + gcol] = v;
            }
        }
    }
}

// ---------------- hyper head (fp32) ----------------
__global__ __launch_bounds__(128) void head_kernel(
    const float* __restrict__ cls, const float* __restrict__ hc_w,
    const float* __restrict__ hc_b, const float* __restrict__ head_w,
    const float* __restrict__ head_b, float* __restrict__ out)
{
    __shared__ float c[192];
    __shared__ float hh[384];
    int b = blockIdx.x, tid = threadIdx.x;
    for (int i = tid; i < 192; i += 128) c[i] = cls[(size_t)b * 192 + i];
    __syncthreads();
    for (int i = tid; i < 384; i += 128) {
        int k = i / 96, o = i % 96;
        float s = hc_b[i];
        #pragma unroll
        for (int j = 0; j < 4; j++) {
            int pp = (k - j + 4) & 3;
            const float* w = hc_w + ((size_t)pp * 96 + o) * 48;
            const float* xv = c + j * 48;
            #pragma unroll
            for (int cc = 0; cc < 48; cc++) s += xv[cc] * w[cc];
        }
        hh[i] = gelu_f(s);
    }
    __syncthreads();
    for (int i = tid; i < 100; i += 128) {
        float s = head_b[i];
        const float* w = head_w + (size_t)i * 384;
        for (int kk = 0; kk < 384; kk++) s += hh[kk] * w[kk];
        out[(size_t)b * 100 + i] = s;
    }
}

extern "C" void kernel_launch(void* const* d_in, const int* in_sizes, int n_in,
                              void* d_out, int out_size, void* d_ws, size_t ws_size,
                              hipStream_t stream)
{
    const float* x        = (const float*)d_in[0];
    const float* conv_w   = (const float*)d_in[1];
    const float* conv_b   = (const float*)d_in[2];
    const float* pe_g     = (const float*)d_in[3];
    const float* pe_b     = (const float*)d_in[4];
    const float* cls_tok  = (const float*)d_in[5];
    const float* pos      = (const float*)d_in[6];
    const float* n1_g     = (const float*)d_in[7];
    const float* n1_b     = (const float*)d_in[8];
    const float* qkv_w    = (const float*)d_in[9];
    const float* temp     = (const float*)d_in[10];
    const float* proj_w   = (const float*)d_in[11];
    const float* proj_b   = (const float*)d_in[12];
    const float* n2_g     = (const float*)d_in[13];
    const float* n2_b     = (const float*)d_in[14];
    const float* gate_w   = (const float*)d_in[15];
    const float* gate_b   = (const float*)d_in[16];
    const float* e_w1     = (const float*)d_in[17];
    const float* e_b1     = (const float*)d_in[18];
    const float* e_w2     = (const float*)d_in[19];
    const float* e_b2     = (const float*)d_in[20];
    const float* attn_sc  = (const float*)d_in[21];
    const float* mlp_sc   = (const float*)d_in[22];
    const float* norm_g   = (const float*)d_in[23];
    const float* norm_b   = (const float*)d_in[24];
    const float* hc_w     = (const float*)d_in[25];
    const float* hc_b     = (const float*)d_in[26];
    const float* head_w   = (const float*)d_in[27];
    const float* head_b   = (const float*)d_in[28];

    // ---- ws layout ----
    char* base = (char*)d_ws;
    float*  t0    = (float*)base;   base += (size_t)ROWS * DD * 4;        // 6.39MB
    float*  t1    = (float*)base;   base += (size_t)ROWS * DD * 4;        // 6.39MB
    float*  ctb   = (float*)base;   base += (size_t)ROWS * 384 * 4;       // 12.8MB
    int*    cnts  = (int*)base;     base += (size_t)12 * 4 * sizeof(int) + 64;
    int*    elist = (int*)base;     base += (size_t)4 * ROWS * 4;         // 133KB
    float*  ewls  = (float*)base;   base += (size_t)4 * ROWS * 4;         // 133KB
    float*  ycls  = (float*)base;   base += (size_t)128 * DD * 4;         // 98KB
    _Float16* yhb = (_Float16*)base; base += (size_t)ROWS * DD * 2;       // 3.19MB
    _Float16* qkvw_h = (_Float16*)base; base += (size_t)12 * 576 * 192 * 2;  // 2.65MB
    _Float16* projw_h = (_Float16*)base; base += (size_t)12 * 192 * 192 * 2; // 0.88MB
    _Float16* ew1_h = (_Float16*)base; base += (size_t)12 * 1536 * 192 * 2;  // 7.1MB
    _Float16* ew2_h = (_Float16*)base; base += (size_t)12 * 192 * 1536 * 2;  // 7.1MB

    hipMemsetAsync(cnts, 0, 12 * 4 * sizeof(int), stream);

    // ---- weight conversion ----
    {
        long n8 = (long)12 * 576 * 192 / 8;
        cvt_h_kernel<<<(int)((n8 + 255) / 256), 256, 0, stream>>>(qkv_w, qkvw_h, n8);
        n8 = (long)12 * 192 * 192 / 8;
        cvt_h_kernel<<<(int)((n8 + 255) / 256), 256, 0, stream>>>(proj_w, projw_h, n8);
        n8 = (long)12 * 1536 * 192 / 8;
        cvt_h_kernel<<<(int)((n8 + 255) / 256), 256, 0, stream>>>(e_w1, ew1_h, n8);
        long n = (long)12 * 192 * 192;
        permw2h_kernel<<<(int)((n + 255) / 256), 256, 0, stream>>>(e_w2, ew2_h);
    }

    embed_kernel<<<128 * 65, 192, 0, stream>>>(x, conv_w, conv_b, pe_g, pe_b, cls_tok, pos, t0);

    float* tbuf[2] = {t0, t1};
    for (int l = 0; l < 12; l++) {
        const float* tin = tbuf[l & 1];
        float* tout = tbuf[1 - (l & 1)];
        layer_attn_kernel<<<256, 256, 0, stream>>>(
            tin, tout, (l > 0) ? ctb : nullptr,
            qkvw_h + (size_t)l * 576 * 192, projw_h + (size_t)l * 192 * 192,
            proj_b + l * DD, attn_sc + l, temp + l * 3,
            n1_g + l * DD, n1_b + l * DD, n2_g + l * DD, n2_b + l * DD,
            gate_w + (size_t)l * 4 * DD, gate_b + l * 4,
            yhb, cnts + l * 4, elist, ewls);
        moe_kernel<<<dim3(260, 4), 256, 0, stream>>>(
            yhb, ew1_h + (size_t)l * 1536 * 192, ew2_h + (size_t)l * 192 * 1536,
            e_b1 + (size_t)l * 1536, e_b2 + (size_t)l * 4 * 192, mlp_sc + l,
            cnts + l * 4, elist, ewls, ctb);
    }

    // final LN on cls rows: fold last MoE contribs (stride-aware)
    ln_kernel<<<32, 256, 0, stream>>>(
        tbuf[0], ctb, ycls, norm_g, norm_b, (long)65 * DD, 128);
    head_kernel<<<128, 128, 0, stream>>>(ycls, hc_w, hc_b, head_w, head_b, (float*)d_out);
}

// Round 11
// 1635.244 us; speedup vs baseline: 2.1101x; 2.1101x over previous
//
#include <hip/hip_runtime.h>
#include <cmath>

// Shapes: B=128, D=192, DEPTH=12, H=3(hd=64), E=4, N=65(tokens), NC=100, WIN_HALF=3
#define ROWS 8320
#define DD   192

typedef __attribute__((ext_vector_type(8))) _Float16 half8;
typedef __attribute__((ext_vector_type(4))) float floatx4;

#define GLD16(gp, lp) __builtin_amdgcn_global_load_lds( \
    (const __attribute__((address_space(1))) void*)(gp), \
    (__attribute__((address_space(3))) void*)(lp), 16, 0, 0)

#define MFMA_F16 __builtin_amdgcn_mfma_f32_16x16x32_f16

__device__ __forceinline__ float gelu_f(float x) {
    return 0.5f * x * (1.0f + erff(x * 0.70710678118654752440f));
}

// block-wide sum for blockDim.x == 192 (embed only)
__device__ __forceinline__ float blk_sum_192(float v, float* sbuf) {
    int tid = threadIdx.x;
    sbuf[tid] = v;
    __syncthreads();
    for (int off = 96; off >= 3; off >>= 1) {
        if (tid < off) sbuf[tid] += sbuf[tid + off];
        __syncthreads();
    }
    float r = sbuf[0] + sbuf[1] + sbuf[2];
    __syncthreads();
    return r;
}

// ---------------- flat fp32 -> fp16 ----------------
__global__ __launch_bounds__(256) void cvt_h_kernel(
    const float* __restrict__ s, _Float16* __restrict__ d, long n8)
{
    long i = (long)blockIdx.x * 256 + threadIdx.x;
    if (i >= n8) return;
    const float* sp = s + i * 8;
    _Float16* dp = d + i * 8;
    #pragma unroll
    for (int j = 0; j < 8; j++) dp[j] = (_Float16)sp[j];
}

// e_w2 (12,4,192,384) -> fp16 cat layout [l][n][K'=1536] with col = e*384+k
__global__ __launch_bounds__(256) void permw2h_kernel(
    const float* __restrict__ s, _Float16* __restrict__ d)
{
    long i = (long)blockIdx.x * 256 + threadIdx.x;   // (l, n, p), p in 0..191
    if (i >= (long)12 * 192 * 192) return;
    int l = (int)(i / (192 * 192));
    int rem = (int)(i % (192 * 192));
    int n = rem / 192, p = rem % 192;
    int c0 = p * 8;
    int e = c0 / 384, k0 = c0 % 384;
    const float* sp = s + (((size_t)l * 4 + e) * 192 + n) * 384 + k0;
    _Float16* dp = d + i * 8;
    #pragma unroll
    for (int j = 0; j < 8; j++) dp[j] = (_Float16)sp[j];
}

// ---------------- patch embed + LN + cls + pos (fp32) ----------------
__global__ __launch_bounds__(192) void embed_kernel(
    const float* __restrict__ x, const float* __restrict__ conv_w,
    const float* __restrict__ conv_b, const float* __restrict__ pe_g,
    const float* __restrict__ pe_b, const float* __restrict__ cls_tok,
    const float* __restrict__ pos, float* __restrict__ t)
{
    __shared__ float patch[48];
    __shared__ float red[192];
    int blk = blockIdx.x;
    int b = blk / 65, n = blk % 65;
    int tid = threadIdx.x;
    if (n == 0) {
        t[(size_t)b * 65 * DD + tid] = cls_tok[tid] + pos[tid];
        return;
    }
    int p = n - 1, gy = p / 8, gx = p % 8;
    if (tid < 48) {
        int c = tid / 16, iy = (tid % 16) / 4, ix = tid % 4;
        patch[tid] = x[((size_t)b * 3 + c) * 1024 + (size_t)(gy * 4 + iy) * 32 + (gx * 4 + ix)];
    }
    __syncthreads();
    float s = conv_b[tid];
    const float* w = conv_w + (size_t)tid * 48;
    #pragma unroll
    for (int f = 0; f < 48; f++) s += patch[f] * w[f];
    float mean = blk_sum_192(s, red) * (1.0f / 192.0f);
    float d = s - mean;
    float var = blk_sum_192(d * d, red) * (1.0f / 192.0f);
    float o = d * rsqrtf(var + 1e-5f) * pe_g[tid] + pe_b[tid];
    t[((size_t)b * 65 + n) * DD + tid] = o + pos[(size_t)n * DD + tid];
}

// ---------------- final LayerNorm (cls rows): wave-per-row + fp16 ctb fold ----------------
__global__ __launch_bounds__(256) void ln_kernel(
    const float* __restrict__ in, const _Float16* __restrict__ ctb,
    float* __restrict__ yf,
    const float* __restrict__ g, const float* __restrict__ bb, long in_stride, int nrows)
{
    int wave = threadIdx.x >> 6, lane = threadIdx.x & 63;
    int r = blockIdx.x * 4 + wave;
    if (r >= nrows) return;
    const float* row = in + (size_t)r * in_stride;
    float v0 = row[lane], v1 = row[lane + 64], v2 = row[lane + 128];
    long gr = (long)r * (in_stride / DD);
    const _Float16* cb = ctb + gr * 384;
    v0 += (float)cb[lane] + (float)cb[192 + lane];
    v1 += (float)cb[lane + 64] + (float)cb[256 + lane];
    v2 += (float)cb[lane + 128] + (float)cb[320 + lane];
    float s = v0 + v1 + v2;
    #pragma unroll
    for (int off = 32; off > 0; off >>= 1) s += __shfl_xor(s, off);
    float mean = s * (1.0f / 192.0f);
    float d0 = v0 - mean, d1 = v1 - mean, d2 = v2 - mean;
    float q = d0 * d0 + d1 * d1 + d2 * d2;
    #pragma unroll
    for (int off = 32; off > 0; off >>= 1) q += __shfl_xor(q, off);
    float rstd = rsqrtf(q * (1.0f / 192.0f) + 1e-5f);
    float* yr = yf + (size_t)r * DD;
    yr[lane] = d0 * rstd * g[lane] + bb[lane];
    yr[lane + 64] = d1 * rstd * g[lane + 64] + bb[lane + 64];
    yr[lane + 128] = d2 * rstd * g[lane + 128] + bb[lane + 128];
}

// ---------------- qkv GEMM with fused LN1: grid (130, 9), 48KB LDS, 3 blocks/CU ----------------
// Each block: LN1 of its 64 rows (reads tA + fp16 ctb fold; 9x redundant across col-groups),
// then 64x64 K=192 fp16 GEMM -> qkvh packed fp16.
__global__ __launch_bounds__(256) void qkv_ln_kernel(
    const float* __restrict__ tA, const _Float16* __restrict__ ctb,
    const _Float16* __restrict__ qw,
    const float* __restrict__ n1g, const float* __restrict__ n1b,
    _Float16* __restrict__ qkvh)
{
    __shared__ __align__(16) _Float16 ylds[64 * 192];   // 24KB, XOR-chunk layout
    __shared__ __align__(16) _Float16 wlds[64 * 192];   // 24KB
    const int tid = threadIdx.x;
    const int lane = tid & 63, wave = tid >> 6;
    const int lr = lane & 15, quad = lane >> 4;
    const int m0 = blockIdx.x * 64, n0 = blockIdx.y * 64;
    const int wm = (wave & 1) * 32, wn = (wave >> 1) * 32;

    // issue W loads (cover: LN phase)
    #pragma unroll
    for (int i = 0; i < 6; i++) {
        int s = (wave * 6 + i) * 64 + lane;
        int rr = s / 24, c = s % 24;
        GLD16(qw + (size_t)(n0 + rr) * 192 + (c ^ (rr & 7)) * 8,
              (char*)wlds + (size_t)s * 16);
    }
    // LN1: 16 rows per wave -> ylds (fp16, XOR-chunk layout)
    for (int rl = wave; rl < 64; rl += 4) {
        int gr = m0 + rl;
        const float* row = tA + (size_t)gr * DD;
        float v0 = row[lane], v1 = row[lane + 64], v2 = row[lane + 128];
        if (ctb) {
            const _Float16* cb = ctb + (size_t)gr * 384;
            v0 += (float)cb[lane] + (float)cb[192 + lane];
            v1 += (float)cb[lane + 64] + (float)cb[256 + lane];
            v2 += (float)cb[lane + 128] + (float)cb[320 + lane];
        }
        float sm = v0 + v1 + v2;
        #pragma unroll
        for (int off = 32; off > 0; off >>= 1) sm += __shfl_xor(sm, off);
        float mean = sm * (1.0f / 192.0f);
        float d0 = v0 - mean, d1 = v1 - mean, d2 = v2 - mean;
        float q = d0 * d0 + d1 * d1 + d2 * d2;
        #pragma unroll
        for (int off = 32; off > 0; off >>= 1) q += __shfl_xor(q, off);
        float rstd = rsqrtf(q * (1.0f / 192.0f) + 1e-5f);
        #pragma unroll
        for (int j = 0; j < 3; j++) {
            int col = lane + j * 64;
            float dv = (j == 0) ? d0 : (j == 1) ? d1 : d2;
            float o = dv * rstd * n1g[col] + n1b[col];
            ylds[((size_t)rl * 24 + ((col >> 3) ^ (rl & 7))) * 8 + (col & 7)] = (_Float16)o;
        }
    }
    __syncthreads();

    floatx4 zero = {0.f, 0.f, 0.f, 0.f};
    floatx4 acc[2][2];
    acc[0][0] = zero; acc[0][1] = zero; acc[1][0] = zero; acc[1][1] = zero;

    #pragma unroll
    for (int m = 0; m < 6; m++) {
        int ch = m * 4 + quad;
        half8 a[2], w[2];
        #pragma unroll
        for (int ti = 0; ti < 2; ti++) {
            int ar = wm + ti * 16 + lr;
            a[ti] = *(const half8*)(ylds + ((size_t)ar * 24 + (ch ^ (ar & 7))) * 8);
            int cr = wn + ti * 16 + lr;
            w[ti] = *(const half8*)(wlds + ((size_t)cr * 24 + (ch ^ (cr & 7))) * 8);
        }
        #pragma unroll
        for (int ti = 0; ti < 2; ti++)
            #pragma unroll
            for (int tj = 0; tj < 2; tj++)
                acc[ti][tj] = MFMA_F16(a[ti], w[tj], acc[ti][tj], 0, 0, 0);
    }

    #pragma unroll
    for (int ti = 0; ti < 2; ti++)
        #pragma unroll
        for (int tj = 0; tj < 2; tj++)
            #pragma unroll
            for (int r = 0; r < 4; r++) {
                int grow = m0 + wm + ti * 16 + quad * 4 + r;
                int gcol = n0 + wn + tj * 16 + lr;
                float v = acc[ti][tj][r];
                float vp = __shfl_xor(v, 1);
                if ((lane & 1) == 0) {
                    union { _Float16 h[2]; unsigned u; } pk;
                    pk.h[0] = (_Float16)v; pk.h[1] = (_Float16)vp;
                    *(unsigned*)(qkvh + (size_t)grow * 576 + (gcol & ~1)) = pk.u;
                }
            }
}

// ---------------- banded attention: fp16 in/out, fp32 compute (r8 proven) ----------------
__global__ __launch_bounds__(256) void attn_kernel(
    const _Float16* __restrict__ qkv, const float* __restrict__ temp,
    _Float16* __restrict__ o)
{
    __shared__ float q[65][64], k[65][64], v[65][64];
    __shared__ float p[65][8];
    int bh = blockIdx.x;
    int b = bh / 3, h = bh % 3;
    int tid = threadIdx.x;
    float coef = 0.125f / temp[h];
    const _Float16* base = qkv + (size_t)b * 65 * 576 + h * 64;
    for (int idx = tid; idx < 65 * 64; idx += 256) {
        int i = idx >> 6, d = idx & 63;
        q[i][d] = (float)base[(size_t)i * 576 + d];
        k[i][d] = (float)base[(size_t)i * 576 + 192 + d];
        v[i][d] = (float)base[(size_t)i * 576 + 384 + d];
    }
    __syncthreads();
    if (tid < 65) {
        int i = tid;
        float sc[7];
        float mx = -1e30f;
        #pragma unroll
        for (int jo = 0; jo < 7; jo++) {
            int j = i - 3 + jo;
            if (j >= 0 && j < 65) {
                float s = 0.f;
                #pragma unroll
                for (int d = 0; d < 64; d++) s += q[i][d] * k[j][d];
                sc[jo] = s * coef;
                mx = fmaxf(mx, sc[jo]);
            } else sc[jo] = -1e30f;
        }
        float sum = 0.f;
        #pragma unroll
        for (int jo = 0; jo < 7; jo++) {
            float e = expf(sc[jo] - mx);
            p[i][jo] = e;
            sum += e;
        }
        float inv = 1.0f / sum;
        #pragma unroll
        for (int jo = 0; jo < 7; jo++) p[i][jo] *= inv;
    }
    __syncthreads();
    for (int idx = tid; idx < 65 * 64; idx += 256) {
        int i = idx >> 6, d = idx & 63;
        float s = 0.f;
        #pragma unroll
        for (int jo = 0; jo < 7; jo++) {
            int j = i - 3 + jo;
            if (j >= 0 && j < 65) s += p[i][jo] * v[j][d];
        }
        o[((size_t)b * 65 + i) * 192 + h * 64 + d] = (_Float16)s;
    }
}

// ---------------- proj + residual + LN2 + gate (fused): grid 260, ~74KB, 2 blocks/CU ----------------
// Block: 32 rows x all 192 cols. t_out = tA + ctb_fold + asc*(o@pw^T + pb); then LN2,
// gate top-2, ballot-aggregated expert-list append (4 atomics/block).
__global__ __launch_bounds__(256) void proj_ln_kernel(
    const _Float16* __restrict__ osph, const _Float16* __restrict__ pw,
    const float* __restrict__ pb, const float* __restrict__ asc,
    const float* __restrict__ tA, const _Float16* __restrict__ ctb,
    float* __restrict__ tB,
    const float* __restrict__ n2g, const float* __restrict__ n2b,
    const float* __restrict__ gwm, const float* __restrict__ gb,
    _Float16* __restrict__ yhb,
    int* __restrict__ cnt, int* __restrict__ list, float* __restrict__ wlist)
{
    __shared__ __align__(16) _Float16 alds[32 * 192];   // 12KB
    __shared__ __align__(16) _Float16 wlds[96 * 192];   // 36KB
    __shared__ float tn[32 * 196];                      // 24.5KB (stride 196: 2-way only)
    __shared__ int   gse[32];
    __shared__ float gw0s[32], gw1s[32];
    const int tid = threadIdx.x;
    const int lane = tid & 63, wave = tid >> 6;
    const int lr = lane & 15, quad = lane >> 4;
    const int r0 = blockIdx.x * 32;
    const int rr0 = (wave & 1) * 16;        // row half
    const int colq = (wave >> 1) * 48;      // col quarter within 96-col stage

    // stage A (attn-out rows)
    #pragma unroll
    for (int i = 0; i < 3; i++) {
        int s = (wave * 3 + i) * 64 + lane;
        int rr = s / 24, c = s % 24;
        GLD16(osph + (size_t)(r0 + rr) * 192 + (c ^ (rr & 7)) * 8,
              (char*)alds + (size_t)s * 16);
    }
    // stage W half 0 (out-cols 0..95)
    #pragma unroll
    for (int i = 0; i < 9; i++) {
        int s = (wave * 9 + i) * 64 + lane;
        int rr = s / 24, c = s % 24;
        GLD16(pw + (size_t)rr * 192 + (c ^ (rr & 7)) * 8,
              (char*)wlds + (size_t)s * 16);
    }
    __syncthreads();

    floatx4 zero = {0.f, 0.f, 0.f, 0.f};
    floatx4 acc[6];
    #pragma unroll
    for (int j = 0; j < 6; j++) acc[j] = zero;

    // stage 0 compute
    #pragma unroll
    for (int m = 0; m < 6; m++) {
        int ch = m * 4 + quad;
        int ar = rr0 + lr;
        half8 a = *(const half8*)(alds + ((size_t)ar * 24 + (ch ^ (ar & 7))) * 8);
        #pragma unroll
        for (int ti = 0; ti < 3; ti++) {
            int n = colq + ti * 16 + lr;
            half8 w = *(const half8*)(wlds + ((size_t)n * 24 + (ch ^ (n & 7))) * 8);
            acc[ti] = MFMA_F16(a, w, acc[ti], 0, 0, 0);
        }
    }
    __syncthreads();   // wlds reads done
    // stage W half 1 (out-cols 96..191)
    #pragma unroll
    for (int i = 0; i < 9; i++) {
        int s = (wave * 9 + i) * 64 + lane;
        int rr = s / 24, c = s % 24;
        GLD16(pw + (size_t)(96 + rr) * 192 + (c ^ (rr & 7)) * 8,
              (char*)wlds + (size_t)s * 16);
    }
    __syncthreads();   // drain
    #pragma unroll
    for (int m = 0; m < 6; m++) {
        int ch = m * 4 + quad;
        int ar = rr0 + lr;
        half8 a = *(const half8*)(alds + ((size_t)ar * 24 + (ch ^ (ar & 7))) * 8);
        #pragma unroll
        for (int ti = 0; ti < 3; ti++) {
            int n = colq + ti * 16 + lr;
            half8 w = *(const half8*)(wlds + ((size_t)n * 24 + (ch ^ (n & 7))) * 8);
            acc[3 + ti] = MFMA_F16(a, w, acc[3 + ti], 0, 0, 0);
        }
    }

    // epilogue: residual + write tB + tn
    float sca = asc[0];
    #pragma unroll
    for (int st = 0; st < 2; st++)
        #pragma unroll
        for (int ti = 0; ti < 3; ti++)
            #pragma unroll
            for (int r = 0; r < 4; r++) {
                int row = rr0 + quad * 4 + r;
                int gcol = st * 96 + colq + ti * 16 + lr;
                int gr = r0 + row;
                float base = tA[(size_t)gr * DD + gcol];
                if (ctb) {
                    const _Float16* cb = ctb + (size_t)gr * 384;
                    base += (float)cb[gcol] + (float)cb[192 + gcol];
                }
                float v = base + sca * (acc[st * 3 + ti][r] + pb[gcol]);
                tB[(size_t)gr * DD + gcol] = v;
                tn[row * 196 + gcol] = v;
            }
    __syncthreads();

    // LN2 + gate scores (8 rows/wave)
    for (int rl = wave; rl < 32; rl += 4) {
        int gr = r0 + rl;
        float v0 = tn[rl * 196 + lane], v1 = tn[rl * 196 + 64 + lane], v2 = tn[rl * 196 + 128 + lane];
        float sm = v0 + v1 + v2;
        #pragma unroll
        for (int off = 32; off > 0; off >>= 1) sm += __shfl_xor(sm, off);
        float mean = sm * (1.0f / 192.0f);
        float d0 = v0 - mean, d1 = v1 - mean, d2 = v2 - mean;
        float q = d0 * d0 + d1 * d1 + d2 * d2;
        #pragma unroll
        for (int off = 32; off > 0; off >>= 1) q += __shfl_xor(q, off);
        float rstd = rsqrtf(q * (1.0f / 192.0f) + 1e-5f);
        float o0 = d0 * rstd * n2g[lane] + n2b[lane];
        float o1 = d1 * rstd * n2g[lane + 64] + n2b[lane + 64];
        float o2 = d2 * rstd * n2g[lane + 128] + n2b[lane + 128];
        _Float16* yr = yhb + (size_t)gr * DD;
        yr[lane] = (_Float16)o0; yr[lane + 64] = (_Float16)o1; yr[lane + 128] = (_Float16)o2;
        float pe[4];
        #pragma unroll
        for (int e = 0; e < 4; e++) {
            const float* w = gwm + (size_t)e * DD;
            pe[e] = o0 * w[lane] + o1 * w[lane + 64] + o2 * w[lane + 128];
            #pragma unroll
            for (int off = 32; off > 0; off >>= 1) pe[e] += __shfl_xor(pe[e], off);
        }
        if (lane == 0) {
            #pragma unroll
            for (int e = 0; e < 4; e++) pe[e] += gb[e];
            float mx = fmaxf(fmaxf(pe[0], pe[1]), fmaxf(pe[2], pe[3]));
            float ex[4];
            #pragma unroll
            for (int e = 0; e < 4; e++) ex[e] = expf(pe[e] - mx);
            int i0 = 0;
            #pragma unroll
            for (int e = 1; e < 4; e++) if (ex[e] > ex[i0]) i0 = e;
            int i1 = (i0 == 0) ? 1 : 0;
            #pragma unroll
            for (int e = 0; e < 4; e++) if (e != i0 && ex[e] > ex[i1]) i1 = e;
            float denom = ex[i0] + ex[i1];
            gse[rl] = i0 | (i1 << 8);
            gw0s[rl] = ex[i0] / denom;
            gw1s[rl] = ex[i1] / denom;
        }
    }
    __syncthreads();

    // ballot-aggregated list append (wave 0; lanes 0..31 = rows)
    if (wave == 0) {
        bool act = lane < 32;
        int sel = act ? gse[lane] : 0;
        int i0 = sel & 0xff, i1 = (sel >> 8) & 0xff;
        unsigned long long lt = (lane == 63) ? ~0ULL >> 1 : (1ULL << lane) - 1ULL;
        #pragma unroll
        for (int e = 0; e < 4; e++) {
            bool s0 = act && (i0 == e);
            bool s1 = act && (i1 == e);
            unsigned long long m0 = __ballot(s0);
            unsigned long long m1 = __ballot(s1);
            int c0 = __popcll(m0), c1 = __popcll(m1);
            int base = 0;
            if (lane == 0) base = atomicAdd(&cnt[e], c0 + c1);
            base = __shfl(base, 0);
            if (s0) {
                int idx = base + __popcll(m0 & lt);
                list[(size_t)e * ROWS + idx] = ((r0 + lane) << 1) | 0;
                wlist[(size_t)e * ROWS + idx] = gw0s[lane];
            }
            if (s1) {
                int idx = base + c0 + __popcll(m1 & lt);
                list[(size_t)e * ROWS + idx] = ((r0 + lane) << 1) | 1;
                wlist[(size_t)e * ROWS + idx] = gw1s[lane];
            }
        }
    }
}

// ---------------- fused MoE (r8 proven) + fp16 ctb packed output ----------------
__global__ __launch_bounds__(256) void moe_kernel(
    const _Float16* __restrict__ yh, const _Float16* __restrict__ w1,
    const _Float16* __restrict__ w2, const float* __restrict__ b1,
    const float* __restrict__ b2, const float* __restrict__ scale,
    const int* __restrict__ cnt, const int* __restrict__ list,
    const float* __restrict__ wlist, _Float16* __restrict__ ctb)
{
    __shared__ __align__(16) _Float16 As[32 * 192];
    __shared__ __align__(16) _Float16 W1s[64 * 192];
    __shared__ __align__(16) _Float16 W2s[192 * 64];
    __shared__ __align__(16) _Float16 Hs[32 * 64];
    __shared__ int   rl[32];
    __shared__ int   rk[32];
    __shared__ float wl[32];
    const int e  = blockIdx.y;
    const int cnte = cnt[e];
    const int r0 = blockIdx.x * 32;
    if (r0 >= cnte) return;
    const int tid = threadIdx.x;
    const int lane = tid & 63, wave = tid >> 6;
    const int lr = lane & 15, quad = lane >> 4;
    const int wr = (wave & 1) * 16;
    const int wc1 = (wave >> 1) * 16;
    const int wc2 = (wave >> 1) * 96;

    if (tid < 32) {
        int sl = r0 + tid;
        bool ok = sl < cnte;
        int v = ok ? list[(size_t)e * ROWS + sl] : 0;
        rl[tid] = v >> 1;
        rk[tid] = ok ? (v & 1) : -1;
        wl[tid] = ok ? wlist[(size_t)e * ROWS + sl] : 0.f;
    }
    __syncthreads();

    #pragma unroll
    for (int i = 0; i < 3; i++) {
        int s = (wave * 3 + i) * 64 + lane;
        int rr = s / 24, c = s % 24;
        GLD16(yh + (size_t)rl[rr] * 192 + (c ^ (rr & 7)) * 8,
              (char*)As + (size_t)(wave * 3 + i) * 1024);
    }
    #pragma unroll
    for (int i = 0; i < 6; i++) {
        int s = (wave * 6 + i) * 64 + lane;
        int rr = s / 24, c = s % 24;
        GLD16(w1 + ((size_t)e * 384 + rr) * 192 + (c ^ (rr & 7)) * 8,
              (char*)W1s + (size_t)(wave * 6 + i) * 1024);
    }
    __syncthreads();

    floatx4 zero = {0.f, 0.f, 0.f, 0.f};
    floatx4 acc2[6];
    #pragma unroll
    for (int j = 0; j < 6; j++) acc2[j] = zero;

    for (int nc = 0; nc < 6; nc++) {
        int ncg = e * 6 + nc;
        #pragma unroll
        for (int i = 0; i < 6; i++) {
            int s = (wave * 6 + i) * 64 + lane;
            int n = s >> 3, c = s & 7;
            GLD16(w2 + (size_t)n * 1536 + (ncg * 8 + (c ^ (n & 7))) * 8,
                  (char*)W2s + (size_t)(wave * 6 + i) * 1024);
        }
        floatx4 acc1[2];
        acc1[0] = zero; acc1[1] = zero;
        #pragma unroll
        for (int m = 0; m < 6; m++) {
            int ar = wr + lr;
            int ch = m * 4 + quad;
            half8 a = *(const half8*)(As + ((size_t)ar * 24 + (ch ^ (ar & 7))) * 8);
            #pragma unroll
            for (int tc = 0; tc < 2; tc++) {
                int cr = wc1 + tc * 32 + lr;
                half8 w = *(const half8*)(W1s + ((size_t)cr * 24 + (ch ^ (cr & 7))) * 8);
                acc1[tc] = MFMA_F16(a, w, acc1[tc], 0, 0, 0);
            }
        }
        #pragma unroll
        for (int tc = 0; tc < 2; tc++)
            #pragma unroll
            for (int r = 0; r < 4; r++) {
                int hrow = wr + quad * 4 + r;
                int hcol = wc1 + tc * 32 + lr;
                float v = gelu_f(acc1[tc][r] + b1[64 * ncg + hcol]) * wl[hrow];
                float vp = __shfl_xor(v, 1);
                if ((lane & 1) == 0) {
                    union { _Float16 h[2]; unsigned u; } pk;
                    pk.h[0] = (_Float16)v;
                    pk.h[1] = (_Float16)vp;
                    int cl = (hcol >> 3) ^ (hrow & 7);
                    *(unsigned*)(Hs + ((size_t)hrow * 8 + cl) * 8 + (hcol & 7)) = pk.u;
                }
            }
        __syncthreads();
        if (nc < 5) {
            #pragma unroll
            for (int i = 0; i < 6; i++) {
                int s = (wave * 6 + i) * 64 + lane;
                int rr = s / 24, c = s % 24;
                GLD16(w1 + ((size_t)e * 384 + (nc + 1) * 64 + rr) * 192 + (c ^ (rr & 7)) * 8,
                      (char*)W1s + (size_t)(wave * 6 + i) * 1024);
            }
        }
        #pragma unroll
        for (int kk = 0; kk < 2; kk++) {
            int ar = wr + lr;
            int ch = kk * 4 + quad;
            half8 a = *(const half8*)(Hs + ((size_t)ar * 8 + (ch ^ (ar & 7))) * 8);
            #pragma unroll
            for (int tj = 0; tj < 6; tj++) {
                int cr = wc2 + tj * 16 + lr;
                half8 w = *(const half8*)(W2s + ((size_t)cr * 8 + (ch ^ (cr & 7))) * 8);
                acc2[tj] = MFMA_F16(a, w, acc2[tj], 0, 0, 0);
            }
        }
        __syncthreads();
    }

    float sc = scale[0];
    #pragma unroll
    for (int tj = 0; tj < 6; tj++) {
        int gcol = wc2 + tj * 16 + lr;
        #pragma unroll
        for (int r = 0; r < 4; r++) {
            int lrow = wr + quad * 4 + r;
            int rank = rk[lrow];
            float v = sc * (acc2[tj][r] + wl[lrow] * b2[e * 192 + gcol]);
            float vp = __shfl_xor(v, 1);
            if (rank >= 0 && (lane & 1) == 0) {
                union { _Float16 h[2]; unsigned u; } pk;
                pk.h[0] = (_Float16)v;
                pk.h[1] = (_Float16)vp;
                *(unsigned*)(ctb + ((size_t)rl[lrow] * 2 + rank) * 192 + (gcol & ~1)) = pk.u;
            }
        }
    }
}

// ---------------- hyper head (fp32) ----------------
__global__ __launch_bounds__(128) void head_kernel(
    const float* __restrict__ cls, const float* __restrict__ hc_w,
    const float* __restrict__ hc_b, const float* __restrict__ head_w,
    const float* __restrict__ head_b, float* __restrict__ out)
{
    __shared__ float c[192];
    __shared__ float hh[384];
    int b = blockIdx.x, tid = threadIdx.x;
    for (int i = tid; i < 192; i += 128) c[i] = cls[(size_t)b * 192 + i];
    __syncthreads();
    for (int i = tid; i < 384; i += 128) {
        int k = i / 96, o = i % 96;
        float s = hc_b[i];
        #pragma unroll
        for (int j = 0; j < 4; j++) {
            int pp = (k - j + 4) & 3;
            const float* w = hc_w + ((size_t)pp * 96 + o) * 48;
            const float* xv = c + j * 48;
            #pragma unroll
            for (int cc = 0; cc < 48; cc++) s += xv[cc] * w[cc];
        }
        hh[i] = gelu_f(s);
    }
    __syncthreads();
    for (int i = tid; i < 100; i += 128) {
        float s = head_b[i];
        const float* w = head_w + (size_t)i * 384;
        for (int kk = 0; kk < 384; kk++) s += hh[kk] * w[kk];
        out[(size_t)b * 100 + i] = s;
    }
}

extern "C" void kernel_launch(void* const* d_in, const int* in_sizes, int n_in,
                              void* d_out, int out_size, void* d_ws, size_t ws_size,
                              hipStream_t stream)
{
    const float* x        = (const float*)d_in[0];
    const float* conv_w   = (const float*)d_in[1];
    const float* conv_b   = (const float*)d_in[2];
    const float* pe_g     = (const float*)d_in[3];
    const float* pe_b     = (const float*)d_in[4];
    const float* cls_tok  = (const float*)d_in[5];
    const float* pos      = (const float*)d_in[6];
    const float* n1_g     = (const float*)d_in[7];
    const float* n1_b     = (const float*)d_in[8];
    const float* qkv_w    = (const float*)d_in[9];
    const float* temp     = (const float*)d_in[10];
    const float* proj_w   = (const float*)d_in[11];
    const float* proj_b   = (const float*)d_in[12];
    const float* n2_g     = (const float*)d_in[13];
    const float* n2_b     = (const float*)d_in[14];
    const float* gate_w   = (const float*)d_in[15];
    const float* gate_b   = (const float*)d_in[16];
    const float* e_w1     = (const float*)d_in[17];
    const float* e_b1     = (const float*)d_in[18];
    const float* e_w2     = (const float*)d_in[19];
    const float* e_b2     = (const float*)d_in[20];
    const float* attn_sc  = (const float*)d_in[21];
    const float* mlp_sc   = (const float*)d_in[22];
    const float* norm_g   = (const float*)d_in[23];
    const float* norm_b   = (const float*)d_in[24];
    const float* hc_w     = (const float*)d_in[25];
    const float* hc_b     = (const float*)d_in[26];
    const float* head_w   = (const float*)d_in[27];
    const float* head_b   = (const float*)d_in[28];

    // ---- ws layout ----
    char* base = (char*)d_ws;
    float*  t0    = (float*)base;   base += (size_t)ROWS * DD * 4;        // 6.39MB
    float*  t1    = (float*)base;   base += (size_t)ROWS * DD * 4;        // 6.39MB
    _Float16* ctb = (_Float16*)base; base += (size_t)ROWS * 384 * 2;      // 6.39MB
    int*    cnts  = (int*)base;     base += (size_t)12 * 4 * sizeof(int) + 64;
    int*    elist = (int*)base;     base += (size_t)4 * ROWS * 4;         // 133KB
    float*  ewls  = (float*)base;   base += (size_t)4 * ROWS * 4;         // 133KB
    float*  ycls  = (float*)base;   base += (size_t)128 * DD * 4;         // 98KB
    _Float16* yhb = (_Float16*)base; base += (size_t)ROWS * DD * 2;       // 3.19MB
    _Float16* qkvh = (_Float16*)base; base += (size_t)ROWS * 576 * 2;     // 9.58MB
    _Float16* osph = (_Float16*)base; base += (size_t)ROWS * DD * 2;      // 3.19MB
    _Float16* qkvw_h = (_Float16*)base; base += (size_t)12 * 576 * 192 * 2;  // 2.65MB
    _Float16* projw_h = (_Float16*)base; base += (size_t)12 * 192 * 192 * 2; // 0.88MB
    _Float16* ew1_h = (_Float16*)base; base += (size_t)12 * 1536 * 192 * 2;  // 7.1MB
    _Float16* ew2_h = (_Float16*)base; base += (size_t)12 * 192 * 1536 * 2;  // 7.1MB

    hipMemsetAsync(cnts, 0, 12 * 4 * sizeof(int), stream);

    // ---- weight conversion ----
    {
        long n8 = (long)12 * 576 * 192 / 8;
        cvt_h_kernel<<<(int)((n8 + 255) / 256), 256, 0, stream>>>(qkv_w, qkvw_h, n8);
        n8 = (long)12 * 192 * 192 / 8;
        cvt_h_kernel<<<(int)((n8 + 255) / 256), 256, 0, stream>>>(proj_w, projw_h, n8);
        n8 = (long)12 * 1536 * 192 / 8;
        cvt_h_kernel<<<(int)((n8 + 255) / 256), 256, 0, stream>>>(e_w1, ew1_h, n8);
        long n = (long)12 * 192 * 192;
        permw2h_kernel<<<(int)((n + 255) / 256), 256, 0, stream>>>(e_w2, ew2_h);
    }

    embed_kernel<<<128 * 65, 192, 0, stream>>>(x, conv_w, conv_b, pe_g, pe_b, cls_tok, pos, t0);

    float* tbuf[2] = {t0, t1};
    for (int l = 0; l < 12; l++) {
        const float* tin = tbuf[l & 1];
        float* tout = tbuf[1 - (l & 1)];
        const _Float16* cb = (l > 0) ? ctb : nullptr;
        qkv_ln_kernel<<<dim3(130, 9), 256, 0, stream>>>(
            tin, cb, qkvw_h + (size_t)l * 576 * 192,
            n1_g + l * DD, n1_b + l * DD, qkvh);
        attn_kernel<<<128 * 3, 256, 0, stream>>>(qkvh, temp + l * 3, osph);
        proj_ln_kernel<<<260, 256, 0, stream>>>(
            osph, projw_h + (size_t)l * 192 * 192, proj_b + l * DD, attn_sc + l,
            tin, cb, tout, n2_g + l * DD, n2_b + l * DD,
            gate_w + (size_t)l * 4 * DD, gate_b + l * 4,
            yhb, cnts + l * 4, elist, ewls);
        moe_kernel<<<dim3(260, 4), 256, 0, stream>>>(
            yhb, ew1_h + (size_t)l * 1536 * 192, ew2_h + (size_t)l * 192 * 1536,
            e_b1 + (size_t)l * 1536, e_b2 + (size_t)l * 4 * 192, mlp_sc + l,
            cnts + l * 4, elist, ewls, ctb);
    }

    // final LN on cls rows: fold last MoE contribs (stride-aware)
    ln_kernel<<<32, 256, 0, stream>>>(
        tbuf[0], ctb, ycls, norm_g, norm_b, (long)65 * DD, 128);
    head_kernel<<<128, 128, 0, stream>>>(ycls, hc_w, hc_b, head_w, head_b, (float*)d_out);
}